// Round 5
// baseline (271.751 us; speedup 1.0000x reference)
//
#include <hip/hip_runtime.h>
#include <hip/hip_bf16.h>
#include <float.h>

// VQ-VAE quantization for x:[8,64,32,32,32] f32, embedding:[512,64] f32.
// Outputs (flat, f32): [0] loss, [1..16777216] quantized [B,C,D,H,W], [16777217] perplexity.

#define EDIM      64
#define NCODES    512
#define SPATIAL   32768        // 32*32*32
#define OUT_ELEMS 16777216     // 8*64*32768
#define NROWS     262144       // 8*32768

typedef __attribute__((ext_vector_type(8))) short  short8;
typedef __attribute__((ext_vector_type(4))) float  float4v;
typedef __attribute__((ext_vector_type(4))) int    int4v;
typedef __attribute__((ext_vector_type(4))) unsigned short ushort4v;

static __device__ __forceinline__ short f32_to_bf16_bits(float f) {
    union { float f; unsigned u; } v; v.f = f;
    unsigned r = v.u + 0x7FFFu + ((v.u >> 16) & 1u);   // RNE, no NaN inputs
    return (short)(r >> 16);
}

// ---------------- prep: bf16(-2*e) table, |e|^2 + 16 bias, zero accumulators
__global__ void vq_prep(const float* __restrict__ emb,
                        float* __restrict__ loss_acc,
                        unsigned* __restrict__ counts,
                        float* __restrict__ eNorm16,
                        short* __restrict__ ebf) {
    int j = blockIdx.x;        // 512 blocks
    int c = threadIdx.x;       // 64 threads = 1 wave
    float v = emb[j * EDIM + c];
    ebf[j * EDIM + c] = f32_to_bf16_bits(-2.0f * v);
    float sq = v * v;
    #pragma unroll
    for (int m = 32; m; m >>= 1) sq += __shfl_xor(sq, m, 64);
    if (c == 0) {
        eNorm16[j] = sq + 16.0f;     // bias so distance keys are positive floats
        counts[j]  = 0u;
        if (j == 0) *loss_acc = 0.0f;
    }
}

// ---------------- argmin: 16 waves share one LDS table copy ----------------
// 1024 thr = 16 waves, 32 rows/wave, 64KB LDS. launch_bounds(1024,8) caps
// VGPR at 256 (need ~110, no spill) and targets 2 blocks/CU (32 waves).
__global__ __launch_bounds__(1024, 8) void vq_argmin(
        const float* __restrict__ x,
        const float* __restrict__ eNorm16,
        const short* __restrict__ ebf,
        unsigned short* __restrict__ idx_out,
        float* __restrict__ loss_acc) {

    __shared__ short ebf_lds[NCODES * EDIM];   // exactly 64 KB, XOR-swizzled rows

    const int tid  = threadIdx.x;              // 1024 threads = 16 waves
    const int wave = tid >> 6;
    const int lane = tid & 63;
    const int lrow = lane & 15;    // A-row / B-col / D-col lane field
    const int lk   = lane >> 4;    // k-chunk / D-row-group lane field
    const int blk  = blockIdx.x;
    const int b    = blk >> 6;            // 64 blocks per batch
    const int s0   = (blk & 63) << 9;     // 512 rows per block (32 per wave)
    const long xbase = ((long)b << 21);   // b*64*32768

    // ---- stage bf16(-2e) table -> LDS (coalesced read, swizzled write) -----
    // LDS byte = j*128 + (co ^ ((j&7)<<4)); read side applies the same XOR.
    {
        const int4v* src = (const int4v*)ebf;
        #pragma unroll
        for (int p = 0; p < 4; ++p) {
            int t  = p * 1024 + tid;             // 16B chunk id (4096 total)
            int j  = t >> 3;
            int co = (t & 7) * 16;
            int4v v = src[t];
            *(int4v*)((char*)ebf_lds + j * 128 + (co ^ ((j & 7) << 4))) = v;
        }
    }

    // ---- A fragments: 2 row-tiles x 2 k-chunks; accumulate sum(x^2) --------
    float  x2 = 0.0f;
    short8 afr[2][2];
    #pragma unroll
    for (int r = 0; r < 2; ++r) {
        const int s = s0 + wave * 32 + r * 16 + lrow;
        #pragma unroll
        for (int kk = 0; kk < 2; ++kk) {
            const float* xp = x + xbase + ((long)(kk * 32 + lk * 8) << 15) + s;
            #pragma unroll
            for (int i = 0; i < 8; ++i) {
                float v = xp[(long)i << 15];
                x2 += v * v;
                afr[r][kk][i] = f32_to_bf16_bits(v);
            }
        }
    }

    // ---- hoist all 32 per-tile eNorm values (L1-hot 2KB) into registers ----
    float en[32];
    #pragma unroll
    for (int jt = 0; jt < 32; ++jt) en[jt] = eNorm16[jt * 16 + lrow];

    __syncthreads();

    // ---- scan 512 codes from LDS; key = float_bits(d+16) low9 <- j ---------
    // Inner loop is pure LDS + MFMA + VALU: no vmem waits on the hot path.
    unsigned key[2][4];
    #pragma unroll
    for (int r = 0; r < 2; ++r)
        #pragma unroll
        for (int q = 0; q < 4; ++q) key[r][q] = 0xFFFFFFFFu;

    const int  swz    = (lrow & 7) << 4;       // j&7 == lrow&7 (jt*16 = 0 mod 8)
    const char* b0base = (const char*)ebf_lds + lrow * 128 + ((lk * 16) ^ swz);
    const char* b1base = (const char*)ebf_lds + lrow * 128 + ((64 + lk * 16) ^ swz);

    #pragma unroll
    for (int jt = 0; jt < 32; ++jt) {
        const int j = jt * 16 + lrow;                 // this lane's code (B col)
        short8 b0 = *(const short8*)(b0base + jt * 2048);
        short8 b1 = *(const short8*)(b1base + jt * 2048);
        float4v cinit = {en[jt], en[jt], en[jt], en[jt]};  // |e|^2+16 folded in C
        #pragma unroll
        for (int r = 0; r < 2; ++r) {
            float4v acc = cinit;
            acc = __builtin_amdgcn_mfma_f32_16x16x32_bf16(afr[r][0], b0, acc, 0, 0, 0);
            acc = __builtin_amdgcn_mfma_f32_16x16x32_bf16(afr[r][1], b1, acc, 0, 0, 0);
            #pragma unroll
            for (int q = 0; q < 4; ++q) {
                unsigned u = (__float_as_uint(acc[q]) & 0xFFFFFE00u) | (unsigned)j;
                key[r][q] = min(key[r][q], u);
            }
        }
    }

    // ---- min butterfly across the 16 code-lanes ----------------------------
    #pragma unroll
    for (int r = 0; r < 2; ++r)
        #pragma unroll
        for (int q = 0; q < 4; ++q) {
            unsigned k = key[r][q];
            #pragma unroll
            for (int m = 1; m < 16; m <<= 1)
                k = min(k, (unsigned)__shfl_xor((int)k, m, 64));
            key[r][q] = k;
        }

    // ---- lrow==0 lanes own 8 rows: write idx, sum min distances ------------
    float smin = 0.0f;
    if (lrow == 0) {
        #pragma unroll
        for (int r = 0; r < 2; ++r) {
            ushort4v iv;
            #pragma unroll
            for (int q = 0; q < 4; ++q) {
                iv[q] = (unsigned short)(key[r][q] & 511u);
                smin += __uint_as_float(key[r][q] & 0xFFFFFE00u) - 16.0f;
            }
            *(ushort4v*)&idx_out[(long)b * SPATIAL + s0 + wave * 32 + r * 16 + lk * 4] = iv;
        }
    }
    float tot = x2 + smin;   // sum (q-x)^2 over wave rows = sum x^2 + sum d_min
    #pragma unroll
    for (int m = 32; m; m >>= 1) tot += __shfl_xor(tot, m, 64);
    if (lane == 0) atomicAdd(loss_acc, tot);   // 16 atomics/block
}

// ---------------- histogram: LDS bins, few global atomics -------------------
__global__ __launch_bounds__(256) void vq_hist(const unsigned short* __restrict__ idx,
                                               unsigned* __restrict__ counts) {
    __shared__ unsigned h[NCODES];
    const int tid = threadIdx.x;
    h[tid] = 0u; h[tid + 256] = 0u;
    __syncthreads();
    const unsigned* p = (const unsigned*)idx;          // 2 ushorts per load
    for (int i = blockIdx.x * 256 + tid; i < NROWS / 2; i += 64 * 256) {
        unsigned v = p[i];
        atomicAdd(&h[v & 0xFFFFu], 1u);
        atomicAdd(&h[v >> 16], 1u);
    }
    __syncthreads();
    atomicAdd(&counts[tid], h[tid]);
    atomicAdd(&counts[tid + 256], h[tid + 256]);
}

// ---------------- scatter: exact f32 codebook rows -> [C][S] output ---------
__global__ __launch_bounds__(256) void vq_scatter(const float* __restrict__ emb,
                                                  const unsigned short* __restrict__ idx,
                                                  float* __restrict__ out) {
    const int tid = threadIdx.x;
    const int blk = blockIdx.x;             // 1024 blocks
    const int b   = blk >> 7;
    const int s0  = (blk & 127) << 8;       // 256 spatial positions per block
    const int j   = idx[(long)b * SPATIAL + s0 + tid];
    const float4v* ep = (const float4v*)(emb + j * EDIM);
    float* obase = out + 1 + ((long)b << 21) + s0 + tid;
    #pragma unroll
    for (int cq = 0; cq < 16; ++cq) {
        float4v ev = ep[cq];                // emb[j][4cq..4cq+3], 16B L2 gather
        #pragma unroll
        for (int k = 0; k < 4; ++k)
            __builtin_nontemporal_store(ev[k], obase + ((long)(cq * 4 + k) << 15));
    }
}

// ---------------- final: scalars -------------------------------------------
__global__ void vq_final(const unsigned* __restrict__ counts,
                         const float* __restrict__ loss_acc,
                         float* __restrict__ out) {
    __shared__ float red[NCODES];
    int t = threadIdx.x;
    float p = (float)counts[t] * (1.0f / 262144.0f);
    red[t] = p * logf(p + 1e-10f);
    __syncthreads();
    for (int m = 256; m; m >>= 1) {
        if (t < m) red[t] += red[t + m];
        __syncthreads();
    }
    if (t == 0) {
        out[0]             = 1.25f * (*loss_acc) * (1.0f / 16777216.0f);
        out[1 + OUT_ELEMS] = expf(-red[0]);
    }
}

extern "C" void kernel_launch(void* const* d_in, const int* in_sizes, int n_in,
                              void* d_out, int out_size, void* d_ws, size_t ws_size,
                              hipStream_t stream) {
    const float* x   = (const float*)d_in[0];
    const float* emb = (const float*)d_in[1];
    float* out = (float*)d_out;

    char* ws = (char*)d_ws;
    float*          loss_acc = (float*)ws;                    // 4 B
    unsigned*       counts   = (unsigned*)(ws + 64);          // 2 KB
    float*          eNorm16  = (float*)(ws + 4096);           // 2 KB
    short*          ebf      = (short*)(ws + 8192);           // 64 KB bf16(-2e)
    unsigned short* idx      = (unsigned short*)(ws + 73728); // 512 KB indices

    vq_prep   <<<NCODES, 64, 0, stream>>>(emb, loss_acc, counts, eNorm16, ebf);
    vq_argmin <<<512, 1024, 0, stream>>>(x, eNorm16, ebf, idx, loss_acc);
    vq_hist   <<<64, 256, 0, stream>>>(idx, counts);
    vq_scatter<<<1024, 256, 0, stream>>>(emb, idx, out);
    vq_final  <<<1, 512, 0, stream>>>(counts, loss_acc, out);
}

// Round 6
// 154.591 us; speedup vs baseline: 1.7579x; 1.7579x over previous
//
#include <hip/hip_runtime.h>
#include <hip/hip_bf16.h>
#include <float.h>

// VQ-VAE quantization for x:[8,64,32,32,32] f32, embedding:[512,64] f32.
// Outputs (flat, f32): [0] loss, [1..16777216] quantized [B,C,D,H,W], [16777217] perplexity.

#define EDIM      64
#define NCODES    512
#define SPATIAL   32768        // 32*32*32
#define OUT_ELEMS 16777216     // 8*64*32768
#define NROWS     262144       // 8*32768

typedef __attribute__((ext_vector_type(8))) short  short8;
typedef __attribute__((ext_vector_type(4))) float  float4v;
typedef __attribute__((ext_vector_type(4))) int    int4v;
typedef __attribute__((ext_vector_type(4))) unsigned short ushort4v;

static __device__ __forceinline__ short f32_to_bf16_bits(float f) {
    union { float f; unsigned u; } v; v.f = f;
    unsigned r = v.u + 0x7FFFu + ((v.u >> 16) & 1u);   // RNE, no NaN inputs
    return (short)(r >> 16);
}

// ---------------- prep: bf16(-2*e) table, |e|^2 + 16 bias, zero accumulators
__global__ void vq_prep(const float* __restrict__ emb,
                        float* __restrict__ loss_acc,
                        unsigned* __restrict__ counts,
                        float* __restrict__ eNorm16,
                        short* __restrict__ ebf) {
    int j = blockIdx.x;        // 512 blocks
    int c = threadIdx.x;       // 64 threads = 1 wave
    float v = emb[j * EDIM + c];
    ebf[j * EDIM + c] = f32_to_bf16_bits(-2.0f * v);
    float sq = v * v;
    #pragma unroll
    for (int m = 32; m; m >>= 1) sq += __shfl_xor(sq, m, 64);
    if (c == 0) {
        eNorm16[j] = sq + 16.0f;     // bias so distance keys are positive floats
        counts[j]  = 0u;
        if (j == 0) *loss_acc = 0.0f;
    }
}

// ---------------- argmin: LDS table, ROLLED jt loop (I$-resident hot loop) --
// R2/R4 both sat at ~80us with every pipe <20% busy and time invariant to
// memory tier: hypothesis = fully-unrolled ~25KB body thrashes the 32KB I$.
// This version keeps the hot loop ~1KB (unroll 4 of 8 iterations).
__global__ __launch_bounds__(512, 2) void vq_argmin(
        const float* __restrict__ x,
        const float* __restrict__ eNorm16,
        const short* __restrict__ ebf,
        unsigned short* __restrict__ idx_out,
        float* __restrict__ loss_acc) {

    __shared__ short ebf_lds[NCODES * EDIM];   // 64 KB, XOR-swizzled rows

    const int tid  = threadIdx.x;              // 512 threads = 8 waves
    const int wave = tid >> 6;
    const int lane = tid & 63;
    const int lrow = lane & 15;    // A-row / B-col / D-col lane field
    const int lk   = lane >> 4;    // k-chunk / D-row-group lane field
    const int blk  = blockIdx.x;
    const int b    = blk >> 7;            // 128 blocks per batch
    const int s0   = (blk & 127) << 8;    // 256 rows per block (32 per wave)
    const long xbase = ((long)b << 21);   // b*64*32768

    // ---- stage bf16(-2e) table -> LDS (coalesced read, swizzled write) -----
    // LDS byte = j*128 + (co ^ ((j&7)<<4)); read side applies the same XOR.
    {
        const int4v* src = (const int4v*)ebf;
        #pragma unroll
        for (int p = 0; p < 8; ++p) {
            int t  = p * 512 + tid;              // 16B chunk id (4096 total)
            int j  = t >> 3;
            int co = (t & 7) * 16;
            int4v v = src[t];
            *(int4v*)((char*)ebf_lds + j * 128 + (co ^ ((j & 7) << 4))) = v;
        }
    }

    // ---- A fragments: 2 row-tiles x 2 k-chunks; accumulate sum(x^2) --------
    float  x2 = 0.0f;
    short8 afr[2][2];
    #pragma unroll
    for (int r = 0; r < 2; ++r) {
        const int s = s0 + wave * 32 + r * 16 + lrow;
        #pragma unroll
        for (int kk = 0; kk < 2; ++kk) {
            const float* xp = x + xbase + ((long)(kk * 32 + lk * 8) << 15) + s;
            #pragma unroll
            for (int i = 0; i < 8; ++i) {
                float v = xp[(long)i << 15];
                x2 += v * v;
                afr[r][kk][i] = f32_to_bf16_bits(v);
            }
        }
    }
    __syncthreads();

    // ---- scan 512 codes from LDS; key = float_bits(d+16) low9 <- j ---------
    unsigned key[2][4];
    #pragma unroll
    for (int r = 0; r < 2; ++r)
        #pragma unroll
        for (int q = 0; q < 4; ++q) key[r][q] = 0xFFFFFFFFu;

    const int  swz    = (lrow & 7) << 4;       // j&7 == lrow&7 (jt*16 = 0 mod 8)
    const char* b0base = (const char*)ebf_lds + lrow * 128 + ((lk * 16) ^ swz);
    const char* b1base = (const char*)ebf_lds + lrow * 128 + ((64 + lk * 16) ^ swz);
    const float* enp   = eNorm16 + lrow;

    #pragma unroll 4                           // ~1KB hot loop, stays in I$
    for (int jt = 0; jt < 32; ++jt) {
        const int j = jt * 16 + lrow;                 // this lane's code (B col)
        short8 b0 = *(const short8*)(b0base + jt * 2048);
        short8 b1 = *(const short8*)(b1base + jt * 2048);
        float  en = enp[jt * 16];                     // L1-hot 2KB, per-iter load
        float4v cinit = {en, en, en, en};             // |e|^2+16 folded into C
        #pragma unroll
        for (int r = 0; r < 2; ++r) {
            float4v acc = cinit;
            acc = __builtin_amdgcn_mfma_f32_16x16x32_bf16(afr[r][0], b0, acc, 0, 0, 0);
            acc = __builtin_amdgcn_mfma_f32_16x16x32_bf16(afr[r][1], b1, acc, 0, 0, 0);
            #pragma unroll
            for (int q = 0; q < 4; ++q) {
                unsigned u = (__float_as_uint(acc[q]) & 0xFFFFFE00u) | (unsigned)j;
                key[r][q] = min(key[r][q], u);
            }
        }
    }

    // ---- min butterfly across the 16 code-lanes ----------------------------
    #pragma unroll
    for (int r = 0; r < 2; ++r)
        #pragma unroll
        for (int q = 0; q < 4; ++q) {
            unsigned k = key[r][q];
            #pragma unroll
            for (int m = 1; m < 16; m <<= 1)
                k = min(k, (unsigned)__shfl_xor((int)k, m, 64));
            key[r][q] = k;
        }

    // ---- lrow==0 lanes own 8 rows: write idx, sum min distances ------------
    float smin = 0.0f;
    if (lrow == 0) {
        #pragma unroll
        for (int r = 0; r < 2; ++r) {
            ushort4v iv;
            #pragma unroll
            for (int q = 0; q < 4; ++q) {
                iv[q] = (unsigned short)(key[r][q] & 511u);
                smin += __uint_as_float(key[r][q] & 0xFFFFFE00u) - 16.0f;
            }
            *(ushort4v*)&idx_out[(long)b * SPATIAL + s0 + wave * 32 + r * 16 + lk * 4] = iv;
        }
    }
    float tot = x2 + smin;   // sum (q-x)^2 over wave rows = sum x^2 + sum d_min
    #pragma unroll
    for (int m = 32; m; m >>= 1) tot += __shfl_xor(tot, m, 64);
    if (lane == 0) atomicAdd(loss_acc, tot);   // 8 atomics/block
}

// ---------------- histogram: LDS bins, few global atomics -------------------
__global__ __launch_bounds__(256) void vq_hist(const unsigned short* __restrict__ idx,
                                               unsigned* __restrict__ counts) {
    __shared__ unsigned h[NCODES];
    const int tid = threadIdx.x;
    h[tid] = 0u; h[tid + 256] = 0u;
    __syncthreads();
    const unsigned* p = (const unsigned*)idx;          // 2 ushorts per load
    for (int i = blockIdx.x * 256 + tid; i < NROWS / 2; i += 64 * 256) {
        unsigned v = p[i];
        atomicAdd(&h[v & 0xFFFFu], 1u);
        atomicAdd(&h[v >> 16], 1u);
    }
    __syncthreads();
    atomicAdd(&counts[tid], h[tid]);
    atomicAdd(&counts[tid + 256], h[tid + 256]);
}

// ---------------- scatter: exact f32 codebook rows -> [C][S] output ---------
__global__ __launch_bounds__(256) void vq_scatter(const float* __restrict__ emb,
                                                  const unsigned short* __restrict__ idx,
                                                  float* __restrict__ out) {
    const int tid = threadIdx.x;
    const int blk = blockIdx.x;             // 1024 blocks
    const int b   = blk >> 7;
    const int s0  = (blk & 127) << 8;       // 256 spatial positions per block
    const int j   = idx[(long)b * SPATIAL + s0 + tid];
    const float4v* ep = (const float4v*)(emb + j * EDIM);
    float* obase = out + 1 + ((long)b << 21) + s0 + tid;
    #pragma unroll
    for (int cq = 0; cq < 16; ++cq) {
        float4v ev = ep[cq];                // emb[j][4cq..4cq+3], 16B L2 gather
        #pragma unroll
        for (int k = 0; k < 4; ++k)
            __builtin_nontemporal_store(ev[k], obase + ((long)(cq * 4 + k) << 15));
    }
}

// ---------------- final: scalars -------------------------------------------
__global__ void vq_final(const unsigned* __restrict__ counts,
                         const float* __restrict__ loss_acc,
                         float* __restrict__ out) {
    __shared__ float red[NCODES];
    int t = threadIdx.x;
    float p = (float)counts[t] * (1.0f / 262144.0f);
    red[t] = p * logf(p + 1e-10f);
    __syncthreads();
    for (int m = 256; m; m >>= 1) {
        if (t < m) red[t] += red[t + m];
        __syncthreads();
    }
    if (t == 0) {
        out[0]             = 1.25f * (*loss_acc) * (1.0f / 16777216.0f);
        out[1 + OUT_ELEMS] = expf(-red[0]);
    }
}

extern "C" void kernel_launch(void* const* d_in, const int* in_sizes, int n_in,
                              void* d_out, int out_size, void* d_ws, size_t ws_size,
                              hipStream_t stream) {
    const float* x   = (const float*)d_in[0];
    const float* emb = (const float*)d_in[1];
    float* out = (float*)d_out;

    char* ws = (char*)d_ws;
    float*          loss_acc = (float*)ws;                    // 4 B
    unsigned*       counts   = (unsigned*)(ws + 64);          // 2 KB
    float*          eNorm16  = (float*)(ws + 4096);           // 2 KB
    short*          ebf      = (short*)(ws + 8192);           // 64 KB bf16(-2e)
    unsigned short* idx      = (unsigned short*)(ws + 73728); // 512 KB indices

    vq_prep   <<<NCODES, 64, 0, stream>>>(emb, loss_acc, counts, eNorm16, ebf);
    vq_argmin <<<1024, 512, 0, stream>>>(x, eNorm16, ebf, idx, loss_acc);
    vq_hist   <<<64, 256, 0, stream>>>(idx, counts);
    vq_scatter<<<1024, 256, 0, stream>>>(emb, idx, out);
    vq_final  <<<1, 512, 0, stream>>>(counts, loss_acc, out);
}

// Round 7
// 101.486 us; speedup vs baseline: 2.6777x; 1.5233x over previous
//
#include <hip/hip_runtime.h>
#include <hip/hip_bf16.h>
#include <float.h>

// VQ-VAE quantization for x:[8,64,32,32,32] f32, embedding:[512,64] f32.
// Outputs (flat, f32): [0] loss, [1..16777216] quantized [B,C,D,H,W], [16777217] perplexity.

#define EDIM      64
#define NCODES    512
#define SPATIAL   32768        // 32*32*32
#define OUT_ELEMS 16777216     // 8*64*32768
#define NROWS     262144       // 8*32768

typedef __attribute__((ext_vector_type(8))) short  short8;
typedef __attribute__((ext_vector_type(4))) float  float4v;
typedef __attribute__((ext_vector_type(4))) int    int4v;
typedef __attribute__((ext_vector_type(4))) unsigned short ushort4v;

static __device__ __forceinline__ unsigned pack_bf16x2(float lo, float hi) {
    union { float f; unsigned u; } a, b; a.f = lo; b.f = hi;
    unsigned ra = (a.u + 0x7FFFu + ((a.u >> 16) & 1u)) >> 16;   // RNE
    unsigned rb = (b.u + 0x7FFFu + ((b.u >> 16) & 1u)) & 0xFFFF0000u;
    return ra | rb;
}

// ---------------- prep: bf16(-2*e) table, |e|^2 + 0.5 key bias, zero counts -
__global__ void vq_prep(const float* __restrict__ emb,
                        unsigned* __restrict__ counts,
                        float* __restrict__ eNormB,
                        short* __restrict__ ebf) {
    int j = blockIdx.x;        // 512 blocks
    int c = threadIdx.x;       // 64 threads = 1 wave
    float v = emb[j * EDIM + c];
    union { float f; unsigned u; } t; t.f = -2.0f * v;
    ebf[j * EDIM + c] = (short)((t.u + 0x7FFFu + ((t.u >> 16) & 1u)) >> 16);
    float sq = v * v;
    #pragma unroll
    for (int m = 32; m; m >>= 1) sq += __shfl_xor(sq, m, 64);
    if (c == 0) {
        eNormB[j] = sq + 0.5f;   // key = 0.5 + |e|^2 - 2x.e  (positive, ~0.5)
        counts[j] = 0u;
    }
}

// ---------------- xprep: x[C][S] -> row-major bf16 xbf[row][64]; sum x^2 ----
__global__ __launch_bounds__(256) void vq_xprep(const float* __restrict__ x,
                                                unsigned short* __restrict__ xbf,
                                                float* __restrict__ xpart) {
    __shared__ float red4[4];
    const int tid = threadIdx.x;
    const int blk = blockIdx.x;           // 1024 blocks
    const int b   = blk >> 7;
    const int s0  = (blk & 127) << 8;     // 256 rows per block, 1 per thread
    const float* xp = x + ((long)b << 21) + s0 + tid;

    unsigned row[32];                     // this thread's row, packed bf16 pairs
    float x2 = 0.0f;
    #pragma unroll
    for (int c = 0; c < 64; c += 2) {
        float v0 = xp[(long)c << 15];         // coalesced: lanes contiguous in s
        float v1 = xp[(long)(c + 1) << 15];
        x2 += v0 * v0 + v1 * v1;
        row[c >> 1] = pack_bf16x2(v0, v1);
    }
    int4v* dst = (int4v*)(xbf + ((long)(b * SPATIAL + s0 + tid) << 6));
    #pragma unroll
    for (int q = 0; q < 8; ++q) dst[q] = *(int4v*)&row[q * 4];

    #pragma unroll
    for (int m = 32; m; m >>= 1) x2 += __shfl_xor(x2, m, 64);
    if ((tid & 63) == 0) red4[tid >> 6] = x2;
    __syncthreads();
    if (tid == 0) xpart[blk] = red4[0] + red4[1] + red4[2] + red4[3];
}

// ---------------- argmin: trivial A-loads, MFMA distances, packed-key min ---
__global__ __launch_bounds__(256) void vq_argmin(
        const unsigned short* __restrict__ xbf,
        const float* __restrict__ eNormB,
        const short* __restrict__ ebf,
        unsigned short* __restrict__ idx_out,
        float* __restrict__ dpart) {

    __shared__ float red4[4];
    const int tid  = threadIdx.x;              // 256 threads = 4 waves
    const int wave = tid >> 6;
    const int lane = tid & 63;
    const int lrow = lane & 15;    // A-row / B-col / D-col lane field
    const int lk   = lane >> 4;    // k-chunk / D-row-group lane field
    const int row0 = blockIdx.x * 256 + wave * 64;   // 1024 blocks, 64 rows/wave

    // ---- A fragments: 4 row-tiles x 2 k-chunks, one dwordx4 each -----------
    short8 afr[4][2];
    #pragma unroll
    for (int r = 0; r < 4; ++r) {
        const long rbase = (long)(row0 + r * 16 + lrow) << 6;
        afr[r][0] = *(const short8*)(xbf + rbase + lk * 8);
        afr[r][1] = *(const short8*)(xbf + rbase + 32 + lk * 8);
    }

    // ---- scan 512 codes; key = float_bits(0.5 + |e|^2 - 2x.e) low9 <- j ----
    unsigned key[4][4];
    #pragma unroll
    for (int r = 0; r < 4; ++r)
        #pragma unroll
        for (int q = 0; q < 4; ++q) key[r][q] = 0xFFFFFFFFu;

    const short8* ebv = (const short8*)ebf;
    #pragma unroll
    for (int jt = 0; jt < 32; ++jt) {
        const int j = jt * 16 + lrow;                 // this lane's code (B col)
        short8 b0 = ebv[j * 8 + lk];                  // channels [lk*8 .. +7]
        short8 b1 = ebv[j * 8 + 4 + lk];              // channels [32+lk*8 .. +7]
        float  en = eNormB[j];
        float4v cinit = {en, en, en, en};
        #pragma unroll
        for (int r = 0; r < 4; ++r) {
            float4v acc = cinit;
            acc = __builtin_amdgcn_mfma_f32_16x16x32_bf16(afr[r][0], b0, acc, 0, 0, 0);
            acc = __builtin_amdgcn_mfma_f32_16x16x32_bf16(afr[r][1], b1, acc, 0, 0, 0);
            #pragma unroll
            for (int q = 0; q < 4; ++q) {
                unsigned u = (__float_as_uint(acc[q]) & 0xFFFFFE00u) | (unsigned)j;
                key[r][q] = min(key[r][q], u);
            }
        }
    }

    // ---- min butterfly across the 16 code-lanes ----------------------------
    #pragma unroll
    for (int r = 0; r < 4; ++r)
        #pragma unroll
        for (int q = 0; q < 4; ++q) {
            unsigned k = key[r][q];
            #pragma unroll
            for (int m = 1; m < 16; m <<= 1)
                k = min(k, (unsigned)__shfl_xor((int)k, m, 64));
            key[r][q] = k;
        }

    // ---- lrow==0 lanes own 16 rows: write idx, sum (d_min - x2 part) -------
    float smin = 0.0f;
    if (lrow == 0) {
        #pragma unroll
        for (int r = 0; r < 4; ++r) {
            ushort4v iv;
            #pragma unroll
            for (int q = 0; q < 4; ++q) {
                iv[q] = (unsigned short)(key[r][q] & 511u);
                smin += __uint_as_float(key[r][q] & 0xFFFFFE00u) - 0.5f;
            }
            *(ushort4v*)&idx_out[row0 + r * 16 + lk * 4] = iv;
        }
    }
    #pragma unroll
    for (int m = 32; m; m >>= 1) smin += __shfl_xor(smin, m, 64);
    if (lane == 0) red4[wave] = smin;
    __syncthreads();
    if (tid == 0) dpart[blockIdx.x] = red4[0] + red4[1] + red4[2] + red4[3];
}

// ---------------- histogram: LDS bins, few global atomics -------------------
__global__ __launch_bounds__(256) void vq_hist(const unsigned short* __restrict__ idx,
                                               unsigned* __restrict__ counts) {
    __shared__ unsigned h[NCODES];
    const int tid = threadIdx.x;
    h[tid] = 0u; h[tid + 256] = 0u;
    __syncthreads();
    const unsigned* p = (const unsigned*)idx;          // 2 ushorts per load
    for (int i = blockIdx.x * 256 + tid; i < NROWS / 2; i += 64 * 256) {
        unsigned v = p[i];
        atomicAdd(&h[v & 0xFFFFu], 1u);
        atomicAdd(&h[v >> 16], 1u);
    }
    __syncthreads();
    atomicAdd(&counts[tid], h[tid]);
    atomicAdd(&counts[tid + 256], h[tid + 256]);
}

// ---------------- scatter: exact f32 codebook rows -> [C][S] output ---------
__global__ __launch_bounds__(256) void vq_scatter(const float* __restrict__ emb,
                                                  const unsigned short* __restrict__ idx,
                                                  float* __restrict__ out) {
    const int tid = threadIdx.x;
    const int blk = blockIdx.x;             // 1024 blocks
    const int b   = blk >> 7;
    const int s0  = (blk & 127) << 8;       // 256 spatial positions per block
    const int j   = idx[(long)b * SPATIAL + s0 + tid];
    const float4v* ep = (const float4v*)(emb + j * EDIM);
    float* obase = out + 1 + ((long)b << 21) + s0 + tid;
    #pragma unroll
    for (int cq = 0; cq < 16; ++cq) {
        float4v ev = ep[cq];                // emb[j][4cq..4cq+3], 16B L2 gather
        #pragma unroll
        for (int k = 0; k < 4; ++k)
            __builtin_nontemporal_store(ev[k], obase + ((long)(cq * 4 + k) << 15));
    }
}

// ---------------- final: scalars -------------------------------------------
__global__ void vq_final(const unsigned* __restrict__ counts,
                         const float* __restrict__ xpart,
                         const float* __restrict__ dpart,
                         float* __restrict__ out) {
    __shared__ float red[NCODES];
    int t = threadIdx.x;                   // 512 threads
    // entropy reduction
    float p = (float)counts[t] * (1.0f / 262144.0f);
    red[t] = p * logf(p + 1e-10f);
    __syncthreads();
    for (int m = 256; m; m >>= 1) {
        if (t < m) red[t] += red[t + m];
        __syncthreads();
    }
    float ppl = expf(-red[0]);
    __syncthreads();
    // loss reduction: sum 1024 xpart + 1024 dpart
    red[t] = xpart[t] + xpart[t + 512] + dpart[t] + dpart[t + 512];
    __syncthreads();
    for (int m = 256; m; m >>= 1) {
        if (t < m) red[t] += red[t + m];
        __syncthreads();
    }
    if (t == 0) {
        out[0]             = 1.25f * red[0] * (1.0f / 16777216.0f);
        out[1 + OUT_ELEMS] = ppl;
    }
}

extern "C" void kernel_launch(void* const* d_in, const int* in_sizes, int n_in,
                              void* d_out, int out_size, void* d_ws, size_t ws_size,
                              hipStream_t stream) {
    const float* x   = (const float*)d_in[0];
    const float* emb = (const float*)d_in[1];
    float* out = (float*)d_out;

    char* ws = (char*)d_ws;
    unsigned*       counts = (unsigned*)(ws + 64);          // 2 KB
    float*          eNormB = (float*)(ws + 4096);           // 2 KB
    short*          ebf    = (short*)(ws + 8192);           // 64 KB bf16(-2e)
    unsigned short* idx    = (unsigned short*)(ws + 73728); // 512 KB indices
    float*          xpart  = (float*)(ws + 598016);         // 4 KB
    float*          dpart  = (float*)(ws + 602112);         // 4 KB

    // xbf (32 MB, bf16 row-major [262144][64]) lives in the out buffer's
    // quantized region (64 MB), which vq_scatter fully overwrites afterwards.
    unsigned short* xbf = (unsigned short*)(out + 4);       // 16B-aligned

    vq_prep   <<<NCODES, 64, 0, stream>>>(emb, counts, eNormB, ebf);
    vq_xprep  <<<1024, 256, 0, stream>>>(x, xbf, xpart);
    vq_argmin <<<1024, 256, 0, stream>>>(xbf, eNormB, ebf, idx, dpart);
    vq_hist   <<<64, 256, 0, stream>>>(idx, counts);
    vq_scatter<<<1024, 256, 0, stream>>>(emb, idx, out);
    vq_final  <<<1, 512, 0, stream>>>(counts, xpart, dpart, out);
}